// Round 1
// 1001.639 us; speedup vs baseline: 1.1347x; 1.1347x over previous
//
#include <hip/hip_runtime.h>
#include <hip/hip_bf16.h>
#include <math.h>

// Problem dims (fixed by reference): G=8, E=8, C=512, H=1024, F=4096
#define GG 8
#define EE 8
#define CC 512
#define HH 1024
#define FF 4096

typedef __attribute__((ext_vector_type(8))) short bf16x8;   // 8 bf16 = 4 VGPRs
typedef __attribute__((ext_vector_type(4))) float f32x4;

__device__ __forceinline__ unsigned short f2bf(float f) {
  unsigned int u = __float_as_uint(f);
  u += 0x7FFFu + ((u >> 16) & 1u);   // RTNE
  return (unsigned short)(u >> 16);
}

__device__ __forceinline__ void gload_lds16(const void* g, void* l) {
  // async global->LDS, 16B/lane; LDS dest is wave-uniform base + lane*16
  __builtin_amdgcn_global_load_lds((__attribute__((address_space(1))) void*)g,
                                   (__attribute__((address_space(3))) void*)l,
                                   16, 0, 0);
}

// fast GELU: x * sigmoid(1.5957691x + 0.071354816x^3); |err vs exact| < ~1e-3
__device__ __forceinline__ float fast_gelu(float x) {
  const float u = x * (1.5957691216057308f + 0.0713548162726009f * x * x);
  return x / (1.0f + __expf(-u));
}

// ---------------- fp32 -> bf16 straight conversion (vectorized) ----------------
__global__ void convert_bf16_kernel(const float4* __restrict__ in,
                                    ushort4* __restrict__ out) {
  const int i = blockIdx.x * blockDim.x + threadIdx.x;
  const float4 v = in[i];
  ushort4 o;
  o.x = f2bf(v.x); o.y = f2bf(v.y); o.z = f2bf(v.z); o.w = f2bf(v.w);
  out[i] = o;
}

// ---------------- fp32 (R x C) -> bf16 (C x R) transpose, per blockIdx.z slab ----------------
__global__ void transpose_bf16(const float* __restrict__ in,
                               unsigned short* __restrict__ out,
                               int R, int C) {
  __shared__ float tile[64][65];                 // +1 pad breaks bank conflicts
  const long ebase = (long)blockIdx.z * R * C;
  const int r0 = blockIdx.y * 64, c0 = blockIdx.x * 64;
  const int t = threadIdx.x;
  const int lr = t >> 4;            // 0..15
  const int lc = (t & 15) * 4;      // 0,4,...,60
#pragma unroll
  for (int p = 0; p < 4; ++p) {
    const int r = lr + p * 16;
    const float4 v = *(const float4*)(in + ebase + (long)(r0 + r) * C + c0 + lc);
    tile[r][lc + 0] = v.x; tile[r][lc + 1] = v.y;
    tile[r][lc + 2] = v.z; tile[r][lc + 3] = v.w;
  }
  __syncthreads();
#pragma unroll
  for (int p = 0; p < 4; ++p) {
    const int c = lr + p * 16;      // output row (original col)
    ushort4 o;
    o.x = f2bf(tile[lc + 0][c]);
    o.y = f2bf(tile[lc + 1][c]);
    o.z = f2bf(tile[lc + 2][c]);
    o.w = f2bf(tile[lc + 3][c]);
    *(ushort4*)(out + ebase + (long)(c0 + c) * R + r0 + lc) = o;
  }
}

// ============================================================================
// 256x256x(BK=64) 8-wave 4-phase GEMM with counted-vmcnt pipeline (T2+T3+T4+T5)
//   - LDS 128 KiB: [buf][khalf] 16KB half-tiles for A and B, double-buffered
//   - half-tile layout: [256 rows][32 k] bf16, byte swizzle o ^= ((o>>7)&7)<<4
//     (involution, within-16B preserving; staged via pre-swizzled GLOBAL source
//      + linear global_load_lds dest; same XOR applied on ds_read side)
//   - per K-tile: 4 phases x {ds_read frags, stage 1 half-tile, s_barrier,
//     lgkmcnt(0), setprio(1) 16xMFMA setprio(0), s_barrier}; vmcnt(4) twice
//     per tile (phases 1 and 3) -> 2-3 phases of load flight across barriers.
//   - raw s_barrier in-loop (NO __syncthreads: it would drain vmcnt(0)).
// ============================================================================

#define SWZ(o) ((o) ^ ((((o) >> 7) & 7) << 4))

#define BARp() __builtin_amdgcn_s_barrier()
#define LGKM0() do { asm volatile("s_waitcnt lgkmcnt(0)" ::: "memory"); \
                     __builtin_amdgcn_sched_barrier(0); } while (0)
#define VMC(n) asm volatile("s_waitcnt vmcnt(" #n ")" ::: "memory")

#define STAGE_A(bf, kh, kt) do { \
    const long _kb = ((long)(kt) * 64 + (kh) * 32) * 2; \
    char* _d = (char*)&sm.s.A[bf][kh][0]; \
    gload_lds16(Ab + (long)sr0 * K2 + _kb + sc0, _d + p0); \
    gload_lds16(Ab + (long)sr1 * K2 + _kb + sc1, _d + p1); \
  } while (0)

#define STAGE_B(bf, kh, kt) do { \
    const long _kb = ((long)(kt) * 64 + (kh) * 32) * 2; \
    char* _d = (char*)&sm.s.B[bf][kh][0]; \
    gload_lds16(Bb + (long)sr0 * K2 + _kb + sc0, _d + p0); \
    gload_lds16(Bb + (long)sr1 * K2 + _kb + sc1, _d + p1); \
  } while (0)

#define LDA_(bf, kh) do { \
    const char* _p = (const char*)&sm.s.A[bf][kh][0]; \
    _Pragma("unroll") \
    for (int _m = 0; _m < 8; ++_m) { \
      const int _r = wm * 128 + _m * 16 + mn; \
      const int _o = SWZ((_r << 6) | (q << 4)); \
      a_fr[_m] = *(const bf16x8*)(_p + _o); \
    } \
  } while (0)

#define LDB_(bf, kh, np) do { \
    const char* _p = (const char*)&sm.s.B[bf][kh][0]; \
    _Pragma("unroll") \
    for (int _j = 0; _j < 2; ++_j) { \
      const int _r = wn * 64 + ((np) * 2 + _j) * 16 + mn; \
      const int _o = SWZ((_r << 6) | (q << 4)); \
      b_fr[_j] = *(const bf16x8*)(_p + _o); \
    } \
  } while (0)

#define MFMA_(np) do { \
    __builtin_amdgcn_s_setprio(1); \
    _Pragma("unroll") \
    for (int _m = 0; _m < 8; ++_m) { \
      acc[_m][(np) * 2 + 0] = __builtin_amdgcn_mfma_f32_16x16x32_bf16( \
          a_fr[_m], b_fr[0], acc[_m][(np) * 2 + 0], 0, 0, 0); \
      acc[_m][(np) * 2 + 1] = __builtin_amdgcn_mfma_f32_16x16x32_bf16( \
          a_fr[_m], b_fr[1], acc[_m][(np) * 2 + 1], 0, 0, 0); \
    } \
    __builtin_amdgcn_s_setprio(0); \
  } while (0)

template <int GELU, int K, int N>
__global__ __launch_bounds__(512, 2)
void ffn_gemm(const unsigned short* __restrict__ A,   // (64*512) x K bf16
              const unsigned short* __restrict__ Bt,  // E x N x K bf16
              const float* __restrict__ bias,         // E x N fp32
              void* __restrict__ Out) {               // (64*512) x N
  __shared__ __align__(16) union SMem {
    struct {
      unsigned short A[2][2][256 * 32];   // [buf][khalf][256 rows][32 k]
      unsigned short B[2][2][256 * 32];
    } s;                                  // 128 KiB
    unsigned short ep[8][32 * 68];        // GELU epilogue, per-wave 32x68-stride
  } sm;

  const int z = blockIdx.z;
  const int g = z & 7;                     // fast: g  (same-e blocks cluster)
  const int e = z >> 3;                    // slow: expert
  const long mBase = (long)(g * EE + e) * 512 + blockIdx.y * 256;
  const int nBase = blockIdx.x * 256;

  const char* Ab = (const char*)(A + mBase * (long)K);
  const char* Bb = (const char*)(Bt + ((long)e * N + nBase) * (long)K);
  const long K2 = (long)K * 2;

  const int tid = threadIdx.x;             // 0..511
  const int lane = tid & 63, wave = tid >> 6;
  const int wm = wave >> 2, wn = wave & 3; // 2(M) x 4(N) waves, 128x64 each
  const int mn = lane & 15, q = lane >> 4;

  // staging map: linear LDS dest byte p -> logical byte SWZ(p) -> global (row, col)
  const int p0 = tid * 16, p1 = p0 + 8192;
  const int o0 = SWZ(p0), o1 = SWZ(p1);
  const int sr0 = o0 >> 6, sc0 = o0 & 63;
  const int sr1 = o1 >> 6, sc1 = o1 & 63;

  bf16x8 a_fr[8];
  bf16x8 b_fr[2];
  f32x4 acc[8][4] = {};

  // prologue: stage K-tile 0 (4 half-tiles = 8 loads), keep kh1 pair in flight
  STAGE_A(0, 0, 0); STAGE_B(0, 0, 0); STAGE_A(0, 1, 0); STAGE_B(0, 1, 0);
  VMC(4);
  BARp();

  constexpr int KT = K / 64;
#pragma unroll 2
  for (int t = 0; t < KT; ++t) {
    const int cur = t & 1, nxt = cur ^ 1;
    const int ktn = (t + 1 == KT) ? 0 : t + 1;   // tail wraps: dead-buffer stage

    // ---- phase 0: khalf 0, n-pair 0 ----
    LDA_(cur, 0);
    LDB_(cur, 0, 0);
    STAGE_A(nxt, 0, ktn);
    BARp(); LGKM0();
    MFMA_(0);
    BARp();
    // ---- phase 1: khalf 0, n-pair 1 ----
    LDB_(cur, 0, 1);
    STAGE_B(nxt, 0, ktn);
    VMC(4);                       // completes this tile's kh1 pair
    BARp(); LGKM0();
    MFMA_(1);
    BARp();
    // ---- phase 2: khalf 1, n-pair 0 ----
    LDA_(cur, 1);
    LDB_(cur, 1, 0);
    STAGE_A(nxt, 1, ktn);
    BARp(); LGKM0();
    MFMA_(0);
    BARp();
    // ---- phase 3: khalf 1, n-pair 1 ----
    LDB_(cur, 1, 1);
    STAGE_B(nxt, 1, ktn);
    VMC(4);                       // completes next tile's kh0 pair
    BARp(); LGKM0();
    MFMA_(1);
    BARp();
  }

  // drain pending async stages before LDS reuse / exit
  asm volatile("s_waitcnt vmcnt(0)" ::: "memory");
  __syncthreads();

  // C/D layout: col = lane&15, row = (lane>>4)*4 + r  [m89/m91-verified]
  if (GELU) {
    unsigned short* ep = &sm.ep[wave][0];
    unsigned short* outp = (unsigned short*)Out;
#pragma unroll
    for (int p2 = 0; p2 < 4; ++p2) {
      // write phase: rows [p2*32, p2*32+32) of this wave's 128x64 tile
#pragma unroll
      for (int mtL = 0; mtL < 2; ++mtL) {
        const int mt = 2 * p2 + mtL;
#pragma unroll
        for (int nt = 0; nt < 4; ++nt) {
          const int n = nBase + wn * 64 + nt * 16 + mn;
          const float bv = bias[(long)e * N + n];
#pragma unroll
          for (int r = 0; r < 4; ++r) {
            const int lr = mtL * 16 + q * 4 + r;
            const float v = fast_gelu(acc[mt][nt][r] + bv);
            ep[lr * 68 + nt * 16 + mn] = f2bf(v);
          }
        }
      }
      // read phase: 8B/lane, 16 lanes cover one 128B row segment
      const int c4 = mn * 4;
#pragma unroll
      for (int i = 0; i < 8; ++i) {
        const int lr2 = i * 4 + q;
        const ushort4 v = *(const ushort4*)&ep[lr2 * 68 + c4];
        const long m = mBase + wm * 128 + p2 * 32 + lr2;
        *(ushort4*)&outp[m * N + nBase + wn * 64 + c4] = v;
      }
    }
  } else {
    float* outp = (float*)Out;
#pragma unroll
    for (int nt = 0; nt < 4; ++nt) {
      const int n = nBase + wn * 64 + nt * 16 + mn;
      const float bv = bias[(long)e * N + n];
#pragma unroll
      for (int mt = 0; mt < 8; ++mt) {
#pragma unroll
        for (int r = 0; r < 4; ++r) {
          const long m = mBase + wm * 128 + mt * 16 + q * 4 + r;
          outp[m * N + n] = acc[mt][nt][r] + bv;
        }
      }
    }
  }
}

extern "C" void kernel_launch(void* const* d_in, const int* in_sizes, int n_in,
                              void* d_out, int out_size, void* d_ws, size_t ws_size,
                              hipStream_t stream) {
  const float* x  = (const float*)d_in[0];  // (G,E,C,H)
  const float* wi = (const float*)d_in[1];  // (E,H,F)
  const float* bi = (const float*)d_in[2];  // (E,F)
  const float* wo = (const float*)d_in[3];  // (E,F,H)
  const float* bo = (const float*)d_in[4];  // (E,H)
  float* out = (float*)d_out;               // (G,E,C,H) fp32

  // workspace layout (stream-ordered reuse of wt):
  //   xb: bf16 inputs            64 MiB @ 0
  //   yb: bf16 gelu intermediate 256 MiB @ 64 MiB
  //   wt: bf16 transposed weight 64 MiB @ 320 MiB (wi_t then wo_t)
  char* ws = (char*)d_ws;
  unsigned short* xb = (unsigned short*)ws;
  unsigned short* yb = (unsigned short*)(ws + (size_t)64 * 1024 * 1024);
  unsigned short* wt = (unsigned short*)(ws + (size_t)320 * 1024 * 1024);

  // 1) inputs fp32 -> bf16
  convert_bf16_kernel<<<32768, 256, 0, stream>>>((const float4*)x, (ushort4*)xb);

  // 2) wi (E,H,F) -> wi_t (E,F,H) bf16
  transpose_bf16<<<dim3(FF / 64, HH / 64, EE), 256, 0, stream>>>(wi, wt, HH, FF);

  // 3) GEMM1 + gelu: yb = gelu(xb @ wi_e + bi)  [K=1024, N=4096]
  ffn_gemm<1, HH, FF><<<dim3(FF / 256, CC / 256, GG * EE), 512, 0, stream>>>(xb, wt, bi, yb);

  // 4) wo (E,F,H) -> wo_t (E,H,F) bf16 (overwrites wt; same stream => ordered)
  transpose_bf16<<<dim3(HH / 64, FF / 64, EE), 256, 0, stream>>>(wo, wt, FF, HH);

  // 5) GEMM2: out = yb @ wo_e + bo  [K=4096, N=1024], fp32 store
  ffn_gemm<0, FF, HH><<<dim3(HH / 256, CC / 256, GG * EE), 512, 0, stream>>>(yb, wt, bo, out);
}